// Round 17
// baseline (256.886 us; speedup 1.0000x reference)
//
#include <hip/hip_runtime.h>

// Problem constants
// x: (8,256,64,64), w_off:(27,256,3,3), w_dcn:(256,256,3,3), w_ct:(256,256,4,4)
// out: (8,256,128,128) fp32

// ws layout (float offsets)
#define OFF_XT   0u
#define SZ_XT    (8u*64u*64u*256u)
#define OFF_Y1   (OFF_XT + SZ_XT)
#define SZ_Y1    SZ_XT
#define OFF_OM   (OFF_Y1 + SZ_Y1)           // om fp32 (8,27,64,64); reused as part2 after dcn2
#define SZ_OM    (8u*27u*4096u)
#define OFF_WD   (OFF_OM + SZ_OM)
#define SZ_WD    (9u*256u*256u)
#define OFF_WC   (OFF_WD + SZ_WD)
#define SZ_WC    (16u*256u*256u)            // 1048576-float slot; wcb uses first 524288 (as ushorts)
#define OFF_WO   (OFF_WC + 524288u)         // wob: 73728 ushorts = 36864 floats
#define OFF_P1   (OFF_WC + 565248u)         // BN1 partials: up to 512 x 512 floats (WC slot tail)
#define OFF_ST   (OFF_WC + SZ_WC)           // stats: 2048 floats

typedef __attribute__((ext_vector_type(8))) short bf16x8;
typedef __attribute__((ext_vector_type(4))) float f32x4;

__device__ __forceinline__ unsigned short f2bf(float f) {
  unsigned int u = __float_as_uint(f);
  u += 0x7fffu + ((u >> 16) & 1u);
  return (unsigned short)(u >> 16);
}

__device__ __forceinline__ unsigned int lerp_pair(unsigned int u00, unsigned int u01,
                                                  unsigned int u10, unsigned int u11,
                                                  float w0, float w1, float w2, float w3) {
  float lo = w0 * __uint_as_float(u00 << 16) + w1 * __uint_as_float(u01 << 16) +
             w2 * __uint_as_float(u10 << 16) + w3 * __uint_as_float(u11 << 16);
  float hi = w0 * __uint_as_float(u00 & 0xffff0000u) + w1 * __uint_as_float(u01 & 0xffff0000u) +
             w2 * __uint_as_float(u10 & 0xffff0000u) + w3 * __uint_as_float(u11 & 0xffff0000u);
  return (unsigned int)f2bf(lo) | ((unsigned int)f2bf(hi) << 16);
}

__device__ __forceinline__ unsigned int norm_pair(unsigned int u, float scx, float shx,
                                                  float scy, float shy) {
  float lo = fmaxf(fmaf(__uint_as_float(u << 16), scx, shx), 0.f);
  float hi = fmaxf(fmaf(__uint_as_float(u & 0xffff0000u), scy, shy), 0.f);
  return (unsigned int)f2bf(lo) | ((unsigned int)f2bf(hi) << 16);
}

// NCHW -> NHWC bf16 transpose of x
__global__ __launch_bounds__(256) void k_transpose_x(const float* __restrict__ x,
                                                     unsigned short* __restrict__ xtb) {
  __shared__ float tile[32][33];
  int ny = blockIdx.x;
  int n = ny >> 6, y = ny & 63;
  int c0 = blockIdx.y * 32;
  int w0 = blockIdx.z * 32;
  int t = threadIdx.x;
  int tx = t & 31, ty = t >> 5;
#pragma unroll
  for (int i = 0; i < 4; ++i) {
    int c = c0 + ty + i * 8;
    tile[ty + i * 8][tx] = x[(((n * 256 + c) * 64 + y) << 6) + w0 + tx];
  }
  __syncthreads();
#pragma unroll
  for (int i = 0; i < 4; ++i) {
    int wl = ty + i * 8;
    xtb[(((n * 64 + y) * 64 + (w0 + wl)) << 8) + c0 + tx] = f2bf(tile[tx][wl]);
  }
}

__global__ void k_prep_wdcn(const float* __restrict__ w, unsigned short* __restrict__ wdb) {
  int idx = blockIdx.x * 256 + threadIdx.x;
  if (idx < 589824) {
    int cil = idx & 31;
    int co = (idx >> 5) & 255;
    int chunk = (idx >> 13) & 7;
    int k = idx >> 16;
    int ci = chunk * 32 + cil;
    wdb[idx] = f2bf(w[(co * 256 + ci) * 9 + k]);
  }
}

__global__ void k_prep_wct(const float* __restrict__ w, unsigned short* __restrict__ wcb) {
  int idx = blockIdx.x * 256 + threadIdx.x;
  int cil = idx & 31;
  int co = (idx >> 5) & 255;
  int chunk = (idx >> 13) & 7;
  int tap = (idx >> 16) & 3;
  int px = (idx >> 18) & 1;
  int py = (idx >> 19) & 1;
  int ci = chunk * 32 + cil;
  int krA = (py == 0) ? 3 : 2, krB = (py == 0) ? 1 : 0;
  int kc0 = (px == 0) ? 3 : 2, kc1 = kc0 - 2;
  int kr = (tap < 2) ? krA : krB;
  int kc = (tap & 1) ? kc1 : kc0;
  float v = w[(ci << 12) + (co << 4) + kr * 4 + kc];
  wcb[idx] = f2bf(v);
}

__global__ void k_prep_woff(const float* __restrict__ w, unsigned short* __restrict__ wob) {
  int idx = blockIdx.x * 256 + threadIdx.x;
  int cil = idx & 31;
  int co = (idx >> 5) & 31;
  int chunk = (idx >> 10) & 7;
  int tap = idx >> 13;
  int ci = chunk * 32 + cil;
  float v = (co < 27) ? w[(co * 256 + ci) * 9 + tap] : 0.f;
  wob[idx] = f2bf(v);
}

// offset conv 256->27(pad 32) via bf16 MFMA. grid 128: bid&7=n, bid>>3=yq (4 rows).
__global__ __launch_bounds__(512) void k_offset_mfma(const unsigned short* __restrict__ xtb,
                                                     const unsigned short* __restrict__ wob,
                                                     const float* __restrict__ b_off,
                                                     float* __restrict__ om) {
  __shared__ unsigned short aLds[6 * 66 * 40];
  __shared__ unsigned short wLds[9 * 32 * 40];
  int bid = blockIdx.x;
  int n = bid & 7, yq = bid >> 3;
  int ybase = yq * 4;
  int t = threadIdx.x;
  int wave = t >> 6, lane = t & 63;
  int lr = wave >> 1, cb = (wave & 1) * 32;
  int l15 = lane & 15, l4 = lane >> 4;
  f32x4 acc[2][2] = {};

  for (int chunk = 0; chunk < 8; ++chunk) {
    __syncthreads();
    for (int task = t; task < 1584; task += 512) {
      int slot = task & 3;
      int rc = task >> 2;
      int c = rc % 66, r = rc / 66;
      int gy = ybase - 1 + r, gx = c - 1;
      uint4 val = make_uint4(0u, 0u, 0u, 0u);
      if (gy >= 0 && gy < 64 && gx >= 0 && gx < 64)
        val = *(const uint4*)&xtb[((size_t)(n * 4096 + gy * 64 + gx) << 8) + chunk * 32 + slot * 8];
      *(uint4*)&aLds[(r * 66 + c) * 40 + slot * 8] = val;
    }
    for (int task = t; task < 1152; task += 512) {
      int sl = task & 3;
      int co = (task >> 2) & 31;
      int tap = task >> 7;
      *(uint4*)&wLds[(tap * 32 + co) * 40 + sl * 8] =
          *(const uint4*)&wob[(size_t)((tap * 8 + chunk) * 32 + co) * 32 + sl * 8];
    }
    __syncthreads();
#pragma unroll
    for (int ky = 0; ky < 3; ++ky)
#pragma unroll
      for (int kx = 0; kx < 3; ++kx) {
        int tap = ky * 3 + kx;
        bf16x8 b0 = *(bf16x8*)&wLds[(tap * 32 + l15) * 40 + l4 * 8];
        bf16x8 b1 = *(bf16x8*)&wLds[(tap * 32 + 16 + l15) * 40 + l4 * 8];
        bf16x8 a0 = *(bf16x8*)&aLds[((lr + ky) * 66 + cb + l15 + kx) * 40 + l4 * 8];
        bf16x8 a1 = *(bf16x8*)&aLds[((lr + ky) * 66 + cb + 16 + l15 + kx) * 40 + l4 * 8];
        acc[0][0] = __builtin_amdgcn_mfma_f32_16x16x32_bf16(a0, b0, acc[0][0], 0, 0, 0);
        acc[0][1] = __builtin_amdgcn_mfma_f32_16x16x32_bf16(a0, b1, acc[0][1], 0, 0, 0);
        acc[1][0] = __builtin_amdgcn_mfma_f32_16x16x32_bf16(a1, b0, acc[1][0], 0, 0, 0);
        acc[1][1] = __builtin_amdgcn_mfma_f32_16x16x32_bf16(a1, b1, acc[1][1], 0, 0, 0);
      }
  }
  int row = ybase + lr;
#pragma unroll
  for (int j = 0; j < 2; ++j) {
    int co = 16 * j + l15;
    if (co < 27) {
      float bias = b_off[co];
      float* dst = om + ((size_t)(n * 27 + co) << 12) + row * 64;
#pragma unroll
      for (int i = 0; i < 2; ++i) {
        f32x4 v = acc[i][j];
        float4 o = make_float4(v[0] + bias, v[1] + bias, v[2] + bias, v[3] + bias);
        *(float4*)&dst[cb + 16 * i + l4 * 4] = o;
      }
    }
  }
}

// DCN v2 via bf16 MFMA, y-pair blocks (128 pos), DOUBLE-BUFFERED aLds:
// one barrier per phase. grid 256: bid&7=n, bid>>3=ypair. setprio around MFMA (T5).
__global__ __launch_bounds__(512) void k_dcn2(const unsigned short* __restrict__ xtb,
                                              const float* __restrict__ om,
                                              const unsigned short* __restrict__ wdb,
                                              const float* __restrict__ b_dcn,
                                              unsigned short* __restrict__ y1r,
                                              float* __restrict__ part1) {
  __shared__ unsigned short aLds[2][128 * 40];  // double-buffered [pos][32ci + 8 pad]
  __shared__ int p_yx[1152];
  __shared__ float p_w[1152 * 4];
  __shared__ float sstat[512];
  int bid = blockIdx.x;
  int n = bid & 7, yp = bid >> 3;
  int ybase = yp * 2;
  int t = threadIdx.x;
  int wave = t >> 6, lane = t & 63;
  int mh = wave >> 2, ns = wave & 3;
  int l15 = lane & 15, l4 = lane >> 4;
  int gp = t >> 2, gq = t & 3;
  int nb = n << 12;
  f32x4 acc[4][4] = {};

  // precompute all 9 taps' sampling params
  for (int i = t; i < 1152; i += 512) {
    int tap = i >> 7, pp = i & 127;
    int ki = tap / 3, kj = tap % 3;
    int yy = ybase + (pp >> 6), xx = pp & 63;
    const float* base = om + (n * 27) * 4096 + (yy << 6) + xx;
    float offy = base[(2 * tap) * 4096];
    float offx = base[(2 * tap + 1) * 4096];
    float mv = base[(18 + tap) * 4096];
    float mask = 1.f / (1.f + expf(-mv));
    float ysf = (float)(yy + ki - 1) + offy;
    float xsf = (float)(xx + kj - 1) + offx;
    float y0f = floorf(ysf), x0f = floorf(xsf);
    float dy = ysf - y0f, dx = xsf - x0f;
    int y0 = (int)y0f, x0 = (int)x0f;
    int y1c = y0 + 1, x1c = x0 + 1;
    float v00 = (y0 >= 0 && y0 < 64 && x0 >= 0 && x0 < 64) ? 1.f : 0.f;
    float v01 = (y0 >= 0 && y0 < 64 && x1c >= 0 && x1c < 64) ? 1.f : 0.f;
    float v10 = (y1c >= 0 && y1c < 64 && x0 >= 0 && x0 < 64) ? 1.f : 0.f;
    float v11 = (y1c >= 0 && y1c < 64 && x1c >= 0 && x1c < 64) ? 1.f : 0.f;
    int cy0 = min(max(y0, 0), 63), cy1 = min(max(y1c, 0), 63);
    int cx0 = min(max(x0, 0), 63), cx1 = min(max(x1c, 0), 63);
    p_yx[i] = cy0 | (cy1 << 8) | (cx0 << 16) | (cx1 << 24);
    p_w[i * 4 + 0] = (1.f - dy) * (1.f - dx) * mask * v00;
    p_w[i * 4 + 1] = (1.f - dy) * dx * mask * v01;
    p_w[i * 4 + 2] = dy * (1.f - dx) * mask * v10;
    p_w[i * 4 + 3] = dy * dx * mask * v11;
  }
  __syncthreads();

  const unsigned short *b00, *b01, *b10, *b11;
  float w0, w1, w2, w3;
#define LOADP(TAP_)                                                                   \
  {                                                                                   \
    int ii = (TAP_) * 128 + gp;                                                       \
    int pk = p_yx[ii];                                                                \
    int y0 = pk & 255, y1c = (pk >> 8) & 255, x0 = (pk >> 16) & 255, x1c = pk >> 24;  \
    w0 = p_w[ii * 4 + 0]; w1 = p_w[ii * 4 + 1];                                       \
    w2 = p_w[ii * 4 + 2]; w3 = p_w[ii * 4 + 3];                                       \
    b00 = xtb + ((size_t)(nb + (y0 << 6) + x0) << 8) + gq * 8;                        \
    b01 = xtb + ((size_t)(nb + (y0 << 6) + x1c) << 8) + gq * 8;                       \
    b10 = xtb + ((size_t)(nb + (y1c << 6) + x0) << 8) + gq * 8;                       \
    b11 = xtb + ((size_t)(nb + (y1c << 6) + x1c) << 8) + gq * 8;                      \
  }
#define WRITE_A(BUF_)                                                                 \
  {                                                                                   \
    uint4 o;                                                                          \
    o.x = lerp_pair(g00.x, g01.x, g10.x, g11.x, w0, w1, w2, w3);                      \
    o.y = lerp_pair(g00.y, g01.y, g10.y, g11.y, w0, w1, w2, w3);                      \
    o.z = lerp_pair(g00.z, g01.z, g10.z, g11.z, w0, w1, w2, w3);                      \
    o.w = lerp_pair(g00.w, g01.w, g10.w, g11.w, w0, w1, w2, w3);                      \
    *(uint4*)&aLds[BUF_][gp * 40 + gq * 8] = o;                                       \
  }
  uint4 g00, g01, g10, g11;
  // prologue: phase 0 A into buf 0, prefetch phase 1 corners
  LOADP(0);
  g00 = *(const uint4*)(b00); g01 = *(const uint4*)(b01);
  g10 = *(const uint4*)(b10); g11 = *(const uint4*)(b11);
  WRITE_A(0);
  g00 = *(const uint4*)(b00 + 32); g01 = *(const uint4*)(b01 + 32);
  g10 = *(const uint4*)(b10 + 32); g11 = *(const uint4*)(b11 + 32);
  __syncthreads();

  for (int p = 0; p < 72; ++p) {
    int cur = p & 1;
    int tap = p >> 3, chunk = p & 7;
    const unsigned short* wp = wdb + (size_t)tap * 65536 + chunk * 8192;
    bf16x8 b[4], a[4];
#pragma unroll
    for (int j = 0; j < 4; ++j)
      b[j] = *(bf16x8*)&wp[(ns * 64 + 16 * j + l15) * 32 + l4 * 8];
#pragma unroll
    for (int i = 0; i < 4; ++i)
      a[i] = *(bf16x8*)&aLds[cur][(mh * 64 + 16 * i + l15) * 40 + l4 * 8];
    __builtin_amdgcn_s_setprio(1);
#pragma unroll
    for (int i = 0; i < 4; ++i)
#pragma unroll
      for (int j = 0; j < 4; ++j)
        acc[i][j] = __builtin_amdgcn_mfma_f32_16x16x32_bf16(a[i], b[j], acc[i][j], 0, 0, 0);
    __builtin_amdgcn_s_setprio(0);
    if (p < 71) {
      WRITE_A(cur ^ 1);
      int q = p + 2;
      if (q < 72) {
        int qt = q >> 3, qc = q & 7;
        if (qc == 0) LOADP(qt);
        int cio = qc * 32;
        g00 = *(const uint4*)(b00 + cio); g01 = *(const uint4*)(b01 + cio);
        g10 = *(const uint4*)(b10 + cio); g11 = *(const uint4*)(b11 + cio);
      }
    }
    __syncthreads(); // single barrier per phase
  }
#undef LOADP
#undef WRITE_A
  // epilogue: bias + raw bf16 store (NHWC) + fused BN1 partial stats
  sstat[t] = 0.f;
  __syncthreads();
  unsigned short* dst = y1r + ((size_t)(n * 4096 + ybase * 64) << 8);
#pragma unroll
  for (int j = 0; j < 4; ++j) {
    int co = ns * 64 + 16 * j + l15;
    float bias = b_dcn[co];
    float ss = 0.f, qq = 0.f;
#pragma unroll
    for (int i = 0; i < 4; ++i)
#pragma unroll
      for (int rr = 0; rr < 4; ++rr) {
        int pos = mh * 64 + 16 * i + l4 * 4 + rr;
        float v = acc[i][j][rr] + bias;
        dst[pos * 256 + co] = f2bf(v);
        ss += v; qq += v * v;
      }
    ss += __shfl_xor(ss, 16); ss += __shfl_xor(ss, 32);
    qq += __shfl_xor(qq, 16); qq += __shfl_xor(qq, 32);
    if (l4 == 0) { atomicAdd(&sstat[co], ss); atomicAdd(&sstat[256 + co], qq); }
  }
  __syncthreads();
  part1[(size_t)bid * 512 + t] = sstat[t];
}

// finalize from per-block partials (nblocks x [256 sum | 256 sumsq]).
__global__ __launch_bounds__(256) void k_finalize_p(const float* __restrict__ part,
                                                    const float* __restrict__ gamma,
                                                    const float* __restrict__ beta,
                                                    float* __restrict__ scsh,
                                                    float inv_cnt, int nblocks) {
  __shared__ float red[512];
  int c = blockIdx.x;
  int t = threadIdx.x;
  float s = 0.f, q = 0.f;
  for (int b = t; b < nblocks; b += 256) {
    s += part[(size_t)b * 512 + c];
    q += part[(size_t)b * 512 + 256 + c];
  }
  red[t] = s;
  red[256 + t] = q;
  __syncthreads();
  for (int w = 128; w > 0; w >>= 1) {
    if (t < w) { red[t] += red[t + w]; red[256 + t] += red[256 + t + w]; }
    __syncthreads();
  }
  if (t == 0) {
    float mu = red[0] * inv_cnt;
    float var = red[256] * inv_cnt - mu * mu;
    float r = rsqrtf(var + 1e-5f);
    float sc = gamma[c] * r;
    scsh[c] = sc;
    scsh[256 + c] = beta[c] - mu * sc;
  }
}

// ConvTranspose 4x4 s2 p1 via bf16 MFMA, u-block=2, DIRECT global W loads,
// BN1 norm+relu fused into A-stage, DOUBLE-BUFFERED aLds (1 barrier/chunk),
// fused BN2 partial stats, setprio around MFMA (T5). grid 512.
__global__ __launch_bounds__(512) void k_convt2(const unsigned short* __restrict__ y1b,
                                               const unsigned short* __restrict__ wcb,
                                               const float* __restrict__ scsh1,
                                               float* __restrict__ out,
                                               float* __restrict__ part2) {
  __shared__ unsigned short sh[16896]; // 33792 B: 2x aLds (2*7920 ush) / epi (33792 B)
  __shared__ float sstat[512];

  int bid = blockIdx.x;
  int n = bid & 7;
  int r2 = bid >> 3;
  int py = r2 & 1;
  int ub = r2 >> 1;        // 0..31
  int u0 = ub * 2;
  int ry0 = u0 - 1 + py;   // rows ry0..ry0+2
  int t = threadIdx.x;
  int wave = t >> 6, lane = t & 63;
  int px_w = wave >> 2, ns = wave & 3;
  int co_base = ns * 64;
  int l15 = lane & 15, l4 = lane >> 4;

  // A-task decode (tasks t and t+512 when t<280), chunk-independent parts
  int as0 = t & 3, arc0 = t >> 2, ac0 = arc0 % 66, ar0 = arc0 / 66;
  int t2 = t + 512;
  int as1 = t2 & 3, arc1 = t2 >> 2, ac1 = arc1 % 66, ar1 = arc1 / 66;
  bool a1v = (t < 280);
  size_t nbase = (size_t)n * 4096;
  int ry_0 = ry0 + ar0, ry_1 = ry0 + ar1;
  bool av0 = (ry_0 >= 0) && (ry_0 < 64) && (ac0 - 1) >= 0 && (ac0 - 1) < 64;
  bool av1 = a1v && (ry_1 >= 0) && (ry_1 < 64) && (ac1 - 1) >= 0 && (ac1 - 1) < 64;
  const unsigned short* asrc0 = y1b + (nbase + (size_t)ry_0 * 64 + (ac0 - 1)) * 256 + as0 * 8;
  const unsigned short* asrc1 = y1b + (nbase + (size_t)ry_1 * 64 + (ac1 - 1)) * 256 + as1 * 8;
  int aoff0 = (ar0 * 66 + ac0) * 40 + as0 * 8;
  int aoff1 = (ar1 * 66 + ac1) * 40 + as1 * 8;

  f32x4 acc[2][4][4] = {}; // 128 VGPRs

  uint4 raw0, raw1;
#define NORMWRITE(BUF_, CHUNK_)                                                          \
  {                                                                                      \
    unsigned short* ab = sh + (BUF_)*7920;                                               \
    int cb0 = (CHUNK_)*32 + as0 * 8;                                                     \
    uint4 val = make_uint4(0u, 0u, 0u, 0u);                                              \
    if (av0) {                                                                           \
      float4 sc0 = *(const float4*)&scsh1[cb0];                                          \
      float4 sc1 = *(const float4*)&scsh1[cb0 + 4];                                      \
      float4 sh0 = *(const float4*)&scsh1[256 + cb0];                                    \
      float4 sh1 = *(const float4*)&scsh1[256 + cb0 + 4];                                \
      val.x = norm_pair(raw0.x, sc0.x, sh0.x, sc0.y, sh0.y);                             \
      val.y = norm_pair(raw0.y, sc0.z, sh0.z, sc0.w, sh0.w);                             \
      val.z = norm_pair(raw0.z, sc1.x, sh1.x, sc1.y, sh1.y);                             \
      val.w = norm_pair(raw0.w, sc1.z, sh1.z, sc1.w, sh1.w);                             \
    }                                                                                    \
    *(uint4*)&ab[aoff0] = val;                                                           \
    if (a1v) {                                                                           \
      int cb1 = (CHUNK_)*32 + as1 * 8;                                                   \
      uint4 v1 = make_uint4(0u, 0u, 0u, 0u);                                             \
      if (av1) {                                                                         \
        float4 sc0 = *(const float4*)&scsh1[cb1];                                        \
        float4 sc1 = *(const float4*)&scsh1[cb1 + 4];                                    \
        float4 sh0 = *(const float4*)&scsh1[256 + cb1];                                  \
        float4 sh1 = *(const float4*)&scsh1[256 + cb1 + 4];                              \
        v1.x = norm_pair(raw1.x, sc0.x, sh0.x, sc0.y, sh0.y);                            \
        v1.y = norm_pair(raw1.y, sc0.z, sh0.z, sc0.w, sh0.w);                            \
        v1.z = norm_pair(raw1.z, sc1.x, sh1.x, sc1.y, sh1.y);                            \
        v1.w = norm_pair(raw1.w, sc1.z, sh1.z, sc1.w, sh1.w);                            \
      }                                                                                  \
      *(uint4*)&ab[aoff1] = v1;                                                          \
    }                                                                                    \
  }

  // prologue: chunk0 raw -> norm+write buf0; prefetch chunk1 raw
  raw0 = av0 ? *(const uint4*)(asrc0) : make_uint4(0u, 0u, 0u, 0u);
  raw1 = av1 ? *(const uint4*)(asrc1) : make_uint4(0u, 0u, 0u, 0u);
  NORMWRITE(0, 0);
  raw0 = av0 ? *(const uint4*)(asrc0 + 32) : make_uint4(0u, 0u, 0u, 0u);
  raw1 = av1 ? *(const uint4*)(asrc1 + 32) : make_uint4(0u, 0u, 0u, 0u);
  __syncthreads();

  for (int chunk = 0; chunk < 8; ++chunk) {
    int cur = chunk & 1;
    const unsigned short* abuf = sh + cur * 7920;
    for (int tap = 0; tap < 4; ++tap) {
      int r_ofs = tap >> 1, s = tap & 1;
      const unsigned short* wsrc =
          wcb + ((size_t)((((py * 2 + px_w) * 4 + tap) * 8 + chunk) * 256 + co_base)) * 32;
      bf16x8 b[4];
#pragma unroll
      for (int j = 0; j < 4; ++j)
        b[j] = *(bf16x8*)&wsrc[(16 * j + l15) * 32 + l4 * 8];
      __builtin_amdgcn_s_setprio(1);
#pragma unroll
      for (int k = 0; k < 2; ++k)
#pragma unroll
        for (int i = 0; i < 4; ++i) {
          int c = 16 * i + l15 + s + px_w;
          bf16x8 a = *(bf16x8*)&abuf[((k + r_ofs) * 66 + c) * 40 + l4 * 8];
#pragma unroll
          for (int j = 0; j < 4; ++j)
            acc[k][i][j] = __builtin_amdgcn_mfma_f32_16x16x32_bf16(a, b[j], acc[k][i][j], 0, 0, 0);
        }
      __builtin_amdgcn_s_setprio(0);
    }
    if (chunk < 7) {
      NORMWRITE(cur ^ 1, chunk + 1);
      if (chunk < 6) {
        int nc = (chunk + 2) * 32;
        raw0 = av0 ? *(const uint4*)(asrc0 + nc) : make_uint4(0u, 0u, 0u, 0u);
        raw1 = av1 ? *(const uint4*)(asrc1 + nc) : make_uint4(0u, 0u, 0u, 0u);
      }
    }
    __syncthreads(); // single barrier per chunk
  }
#undef NORMWRITE

  // epilogue: px interleave via LDS, contiguous stores, fused BN2 partials.
  sstat[t] = 0.f;
  float* epi = (float*)sh;
#pragma unroll
  for (int k = 0; k < 2; ++k) {
    int oy = 2 * (u0 + k) + py;
    for (int qt = 0; qt < 4; ++qt) {
      __syncthreads();
      if (ns == qt) {
#pragma unroll
        for (int i = 0; i < 4; ++i)
#pragma unroll
          for (int j = 0; j < 4; ++j) {
            int co_l = 16 * j + l15;
            int vbase = 16 * i + l4 * 4;
            *(f32x4*)&epi[co_l * 132 + px_w * 64 + vbase] = acc[k][i][j];
          }
      }
      __syncthreads();
#pragma unroll
      for (int it = 0; it < 4; ++it) {
        int task = it * 512 + t;
        int q = task & 31;
        int co_l = task >> 5;
        int co = qt * 64 + co_l;
        float e00 = epi[co_l * 132 + 2 * q];
        float e01 = epi[co_l * 132 + 2 * q + 1];
        float e10 = epi[co_l * 132 + 64 + 2 * q];
        float e11 = epi[co_l * 132 + 64 + 2 * q + 1];
        float4 vv = make_float4(e00, e10, e01, e11);
        *(float4*)&out[((size_t)(n * 256 + co) * 128 + oy) * 128 + 4 * q] = vv;
        float ss = e00 + e01 + e10 + e11;
        float qq = e00 * e00 + e01 * e01 + e10 * e10 + e11 * e11;
        ss += __shfl_xor(ss, 1);  qq += __shfl_xor(qq, 1);
        ss += __shfl_xor(ss, 2);  qq += __shfl_xor(qq, 2);
        ss += __shfl_xor(ss, 4);  qq += __shfl_xor(qq, 4);
        ss += __shfl_xor(ss, 8);  qq += __shfl_xor(qq, 8);
        ss += __shfl_xor(ss, 16); qq += __shfl_xor(qq, 16);
        if ((lane & 31) == 0) {
          atomicAdd(&sstat[co], ss);
          atomicAdd(&sstat[256 + co], qq);
        }
      }
    }
  }
  __syncthreads();
  part2[(size_t)bid * 512 + t] = sstat[t];
}

__global__ void k_norm_nchw(float* __restrict__ buf, const float* __restrict__ scsh) {
  int idx = blockIdx.x * 256 + threadIdx.x;
  int c = (idx >> 12) & 255;
  float sc = scsh[c], sh = scsh[256 + c];
  float4 v = *(float4*)&buf[(size_t)idx * 4];
  v.x = fmaxf(fmaf(v.x, sc, sh), 0.f);
  v.y = fmaxf(fmaf(v.y, sc, sh), 0.f);
  v.z = fmaxf(fmaf(v.z, sc, sh), 0.f);
  v.w = fmaxf(fmaf(v.w, sc, sh), 0.f);
  *(float4*)&buf[(size_t)idx * 4] = v;
}

extern "C" void kernel_launch(void* const* d_in, const int* in_sizes, int n_in,
                              void* d_out, int out_size, void* d_ws, size_t ws_size,
                              hipStream_t stream) {
  (void)in_sizes; (void)n_in; (void)out_size; (void)ws_size;
  const float* x      = (const float*)d_in[0];
  const float* w_off  = (const float*)d_in[1];
  const float* b_off  = (const float*)d_in[2];
  const float* w_dcn  = (const float*)d_in[3];
  const float* b_dcn  = (const float*)d_in[4];
  const float* gamma1 = (const float*)d_in[5];
  const float* beta1  = (const float*)d_in[6];
  const float* w_ct   = (const float*)d_in[7];
  const float* gamma2 = (const float*)d_in[8];
  const float* beta2  = (const float*)d_in[9];
  float* ws  = (float*)d_ws;
  unsigned short* xtb = (unsigned short*)(ws + OFF_XT);
  unsigned short* y1r = (unsigned short*)(ws + OFF_Y1);
  float* om  = ws + OFF_OM;           // reused as part2 after dcn2
  unsigned short* wdb = (unsigned short*)(ws + OFF_WD);
  unsigned short* wcb = (unsigned short*)(ws + OFF_WC);
  unsigned short* wob = (unsigned short*)(ws + OFF_WO);
  float* st  = ws + OFF_ST;
  float* p1  = ws + OFF_P1;
  float* out = (float*)d_out;

  k_transpose_x<<<dim3(512, 8, 2), 256, 0, stream>>>(x, xtb);
  k_prep_wdcn<<<2304, 256, 0, stream>>>(w_dcn, wdb);
  k_prep_wct<<<4096, 256, 0, stream>>>(w_ct, wcb);
  k_prep_woff<<<288, 256, 0, stream>>>(w_off, wob);
  k_offset_mfma<<<128, 512, 0, stream>>>(xtb, wob, b_off, om);
  k_dcn2<<<256, 512, 0, stream>>>(xtb, om, wdb, b_dcn, y1r, p1);
  k_finalize_p<<<256, 256, 0, stream>>>(p1, gamma1, beta1, st + 512, 1.f / 32768.f, 256);
  k_convt2<<<512, 512, 0, stream>>>(y1r, wcb, st + 512, out, om); // om reused as part2
  k_finalize_p<<<256, 256, 0, stream>>>(om, gamma2, beta2, st + 1536, 1.f / 131072.f, 512);
  k_norm_nchw<<<32768, 256, 0, stream>>>(out, st + 1536);
}

// Round 18
// 248.488 us; speedup vs baseline: 1.0338x; 1.0338x over previous
//
#include <hip/hip_runtime.h>

// Problem constants
// x: (8,256,64,64), w_off:(27,256,3,3), w_dcn:(256,256,3,3), w_ct:(256,256,4,4)
// out: (8,256,128,128) fp32

// ws layout (float offsets)
#define OFF_XT   0u
#define SZ_XT    (8u*64u*64u*256u)
#define OFF_Y1   (OFF_XT + SZ_XT)
#define SZ_Y1    SZ_XT
#define OFF_OM   (OFF_Y1 + SZ_Y1)           // om fp32 (8,27,64,64); reused as part2 after dcn2
#define SZ_OM    (8u*27u*4096u)
#define OFF_WD   (OFF_OM + SZ_OM)
#define SZ_WD    (9u*256u*256u)
#define OFF_WC   (OFF_WD + SZ_WD)
#define SZ_WC    (16u*256u*256u)            // 1048576-float slot; wcb uses first 524288 (as ushorts)
#define OFF_WO   (OFF_WC + 524288u)         // wob: 73728 ushorts = 36864 floats
#define OFF_P1   (OFF_WC + 565248u)         // BN1 partials: up to 512 x 512 floats (WC slot tail)
#define OFF_ST   (OFF_WC + SZ_WC)           // stats: 2048 floats

typedef __attribute__((ext_vector_type(8))) short bf16x8;
typedef __attribute__((ext_vector_type(4))) float f32x4;

__device__ __forceinline__ unsigned short f2bf(float f) {
  unsigned int u = __float_as_uint(f);
  u += 0x7fffu + ((u >> 16) & 1u);
  return (unsigned short)(u >> 16);
}

__device__ __forceinline__ unsigned int lerp_pair(unsigned int u00, unsigned int u01,
                                                  unsigned int u10, unsigned int u11,
                                                  float w0, float w1, float w2, float w3) {
  float lo = w0 * __uint_as_float(u00 << 16) + w1 * __uint_as_float(u01 << 16) +
             w2 * __uint_as_float(u10 << 16) + w3 * __uint_as_float(u11 << 16);
  float hi = w0 * __uint_as_float(u00 & 0xffff0000u) + w1 * __uint_as_float(u01 & 0xffff0000u) +
             w2 * __uint_as_float(u10 & 0xffff0000u) + w3 * __uint_as_float(u11 & 0xffff0000u);
  return (unsigned int)f2bf(lo) | ((unsigned int)f2bf(hi) << 16);
}

__device__ __forceinline__ unsigned int norm_pair(unsigned int u, float scx, float shx,
                                                  float scy, float shy) {
  float lo = fmaxf(fmaf(__uint_as_float(u << 16), scx, shx), 0.f);
  float hi = fmaxf(fmaf(__uint_as_float(u & 0xffff0000u), scy, shy), 0.f);
  return (unsigned int)f2bf(lo) | ((unsigned int)f2bf(hi) << 16);
}

// NCHW -> NHWC bf16 transpose of x
__global__ __launch_bounds__(256) void k_transpose_x(const float* __restrict__ x,
                                                     unsigned short* __restrict__ xtb) {
  __shared__ float tile[32][33];
  int ny = blockIdx.x;
  int n = ny >> 6, y = ny & 63;
  int c0 = blockIdx.y * 32;
  int w0 = blockIdx.z * 32;
  int t = threadIdx.x;
  int tx = t & 31, ty = t >> 5;
#pragma unroll
  for (int i = 0; i < 4; ++i) {
    int c = c0 + ty + i * 8;
    tile[ty + i * 8][tx] = x[(((n * 256 + c) * 64 + y) << 6) + w0 + tx];
  }
  __syncthreads();
#pragma unroll
  for (int i = 0; i < 4; ++i) {
    int wl = ty + i * 8;
    xtb[(((n * 64 + y) * 64 + (w0 + wl)) << 8) + c0 + tx] = f2bf(tile[tx][wl]);
  }
}

__global__ void k_prep_wdcn(const float* __restrict__ w, unsigned short* __restrict__ wdb) {
  int idx = blockIdx.x * 256 + threadIdx.x;
  if (idx < 589824) {
    int cil = idx & 31;
    int co = (idx >> 5) & 255;
    int chunk = (idx >> 13) & 7;
    int k = idx >> 16;
    int ci = chunk * 32 + cil;
    wdb[idx] = f2bf(w[(co * 256 + ci) * 9 + k]);
  }
}

__global__ void k_prep_wct(const float* __restrict__ w, unsigned short* __restrict__ wcb) {
  int idx = blockIdx.x * 256 + threadIdx.x;
  int cil = idx & 31;
  int co = (idx >> 5) & 255;
  int chunk = (idx >> 13) & 7;
  int tap = (idx >> 16) & 3;
  int px = (idx >> 18) & 1;
  int py = (idx >> 19) & 1;
  int ci = chunk * 32 + cil;
  int krA = (py == 0) ? 3 : 2, krB = (py == 0) ? 1 : 0;
  int kc0 = (px == 0) ? 3 : 2, kc1 = kc0 - 2;
  int kr = (tap < 2) ? krA : krB;
  int kc = (tap & 1) ? kc1 : kc0;
  float v = w[(ci << 12) + (co << 4) + kr * 4 + kc];
  wcb[idx] = f2bf(v);
}

__global__ void k_prep_woff(const float* __restrict__ w, unsigned short* __restrict__ wob) {
  int idx = blockIdx.x * 256 + threadIdx.x;
  int cil = idx & 31;
  int co = (idx >> 5) & 31;
  int chunk = (idx >> 10) & 7;
  int tap = idx >> 13;
  int ci = chunk * 32 + cil;
  float v = (co < 27) ? w[(co * 256 + ci) * 9 + tap] : 0.f;
  wob[idx] = f2bf(v);
}

// offset conv 256->27(pad 32) via bf16 MFMA. grid 128: bid&7=n, bid>>3=yq (4 rows).
__global__ __launch_bounds__(512) void k_offset_mfma(const unsigned short* __restrict__ xtb,
                                                     const unsigned short* __restrict__ wob,
                                                     const float* __restrict__ b_off,
                                                     float* __restrict__ om) {
  __shared__ unsigned short aLds[6 * 66 * 40];
  __shared__ unsigned short wLds[9 * 32 * 40];
  int bid = blockIdx.x;
  int n = bid & 7, yq = bid >> 3;
  int ybase = yq * 4;
  int t = threadIdx.x;
  int wave = t >> 6, lane = t & 63;
  int lr = wave >> 1, cb = (wave & 1) * 32;
  int l15 = lane & 15, l4 = lane >> 4;
  f32x4 acc[2][2] = {};

  for (int chunk = 0; chunk < 8; ++chunk) {
    __syncthreads();
    for (int task = t; task < 1584; task += 512) {
      int slot = task & 3;
      int rc = task >> 2;
      int c = rc % 66, r = rc / 66;
      int gy = ybase - 1 + r, gx = c - 1;
      uint4 val = make_uint4(0u, 0u, 0u, 0u);
      if (gy >= 0 && gy < 64 && gx >= 0 && gx < 64)
        val = *(const uint4*)&xtb[((size_t)(n * 4096 + gy * 64 + gx) << 8) + chunk * 32 + slot * 8];
      *(uint4*)&aLds[(r * 66 + c) * 40 + slot * 8] = val;
    }
    for (int task = t; task < 1152; task += 512) {
      int sl = task & 3;
      int co = (task >> 2) & 31;
      int tap = task >> 7;
      *(uint4*)&wLds[(tap * 32 + co) * 40 + sl * 8] =
          *(const uint4*)&wob[(size_t)((tap * 8 + chunk) * 32 + co) * 32 + sl * 8];
    }
    __syncthreads();
#pragma unroll
    for (int ky = 0; ky < 3; ++ky)
#pragma unroll
      for (int kx = 0; kx < 3; ++kx) {
        int tap = ky * 3 + kx;
        bf16x8 b0 = *(bf16x8*)&wLds[(tap * 32 + l15) * 40 + l4 * 8];
        bf16x8 b1 = *(bf16x8*)&wLds[(tap * 32 + 16 + l15) * 40 + l4 * 8];
        bf16x8 a0 = *(bf16x8*)&aLds[((lr + ky) * 66 + cb + l15 + kx) * 40 + l4 * 8];
        bf16x8 a1 = *(bf16x8*)&aLds[((lr + ky) * 66 + cb + 16 + l15 + kx) * 40 + l4 * 8];
        acc[0][0] = __builtin_amdgcn_mfma_f32_16x16x32_bf16(a0, b0, acc[0][0], 0, 0, 0);
        acc[0][1] = __builtin_amdgcn_mfma_f32_16x16x32_bf16(a0, b1, acc[0][1], 0, 0, 0);
        acc[1][0] = __builtin_amdgcn_mfma_f32_16x16x32_bf16(a1, b0, acc[1][0], 0, 0, 0);
        acc[1][1] = __builtin_amdgcn_mfma_f32_16x16x32_bf16(a1, b1, acc[1][1], 0, 0, 0);
      }
  }
  int row = ybase + lr;
#pragma unroll
  for (int j = 0; j < 2; ++j) {
    int co = 16 * j + l15;
    if (co < 27) {
      float bias = b_off[co];
      float* dst = om + ((size_t)(n * 27 + co) << 12) + row * 64;
#pragma unroll
      for (int i = 0; i < 2; ++i) {
        f32x4 v = acc[i][j];
        float4 o = make_float4(v[0] + bias, v[1] + bias, v[2] + bias, v[3] + bias);
        *(float4*)&dst[cb + 16 * i + l4 * 4] = o;
      }
    }
  }
}

// DCN v2 via bf16 MFMA, y-pair blocks (128 pos), DOUBLE-BUFFERED aLds:
// one barrier per phase. grid 256: bid&7=n, bid>>3=ypair.
__global__ __launch_bounds__(512) void k_dcn2(const unsigned short* __restrict__ xtb,
                                              const float* __restrict__ om,
                                              const unsigned short* __restrict__ wdb,
                                              const float* __restrict__ b_dcn,
                                              unsigned short* __restrict__ y1r,
                                              float* __restrict__ part1) {
  __shared__ unsigned short aLds[2][128 * 40];  // double-buffered [pos][32ci + 8 pad]
  __shared__ int p_yx[1152];
  __shared__ float p_w[1152 * 4];
  __shared__ float sstat[512];
  int bid = blockIdx.x;
  int n = bid & 7, yp = bid >> 3;
  int ybase = yp * 2;
  int t = threadIdx.x;
  int wave = t >> 6, lane = t & 63;
  int mh = wave >> 2, ns = wave & 3;
  int l15 = lane & 15, l4 = lane >> 4;
  int gp = t >> 2, gq = t & 3;
  int nb = n << 12;
  f32x4 acc[4][4] = {};

  // precompute all 9 taps' sampling params
  for (int i = t; i < 1152; i += 512) {
    int tap = i >> 7, pp = i & 127;
    int ki = tap / 3, kj = tap % 3;
    int yy = ybase + (pp >> 6), xx = pp & 63;
    const float* base = om + (n * 27) * 4096 + (yy << 6) + xx;
    float offy = base[(2 * tap) * 4096];
    float offx = base[(2 * tap + 1) * 4096];
    float mv = base[(18 + tap) * 4096];
    float mask = 1.f / (1.f + expf(-mv));
    float ysf = (float)(yy + ki - 1) + offy;
    float xsf = (float)(xx + kj - 1) + offx;
    float y0f = floorf(ysf), x0f = floorf(xsf);
    float dy = ysf - y0f, dx = xsf - x0f;
    int y0 = (int)y0f, x0 = (int)x0f;
    int y1c = y0 + 1, x1c = x0 + 1;
    float v00 = (y0 >= 0 && y0 < 64 && x0 >= 0 && x0 < 64) ? 1.f : 0.f;
    float v01 = (y0 >= 0 && y0 < 64 && x1c >= 0 && x1c < 64) ? 1.f : 0.f;
    float v10 = (y1c >= 0 && y1c < 64 && x0 >= 0 && x0 < 64) ? 1.f : 0.f;
    float v11 = (y1c >= 0 && y1c < 64 && x1c >= 0 && x1c < 64) ? 1.f : 0.f;
    int cy0 = min(max(y0, 0), 63), cy1 = min(max(y1c, 0), 63);
    int cx0 = min(max(x0, 0), 63), cx1 = min(max(x1c, 0), 63);
    p_yx[i] = cy0 | (cy1 << 8) | (cx0 << 16) | (cx1 << 24);
    p_w[i * 4 + 0] = (1.f - dy) * (1.f - dx) * mask * v00;
    p_w[i * 4 + 1] = (1.f - dy) * dx * mask * v01;
    p_w[i * 4 + 2] = dy * (1.f - dx) * mask * v10;
    p_w[i * 4 + 3] = dy * dx * mask * v11;
  }
  __syncthreads();

  const unsigned short *b00, *b01, *b10, *b11;
  float w0, w1, w2, w3;
#define LOADP(TAP_)                                                                   \
  {                                                                                   \
    int ii = (TAP_) * 128 + gp;                                                       \
    int pk = p_yx[ii];                                                                \
    int y0 = pk & 255, y1c = (pk >> 8) & 255, x0 = (pk >> 16) & 255, x1c = pk >> 24;  \
    w0 = p_w[ii * 4 + 0]; w1 = p_w[ii * 4 + 1];                                       \
    w2 = p_w[ii * 4 + 2]; w3 = p_w[ii * 4 + 3];                                       \
    b00 = xtb + ((size_t)(nb + (y0 << 6) + x0) << 8) + gq * 8;                        \
    b01 = xtb + ((size_t)(nb + (y0 << 6) + x1c) << 8) + gq * 8;                       \
    b10 = xtb + ((size_t)(nb + (y1c << 6) + x0) << 8) + gq * 8;                       \
    b11 = xtb + ((size_t)(nb + (y1c << 6) + x1c) << 8) + gq * 8;                      \
  }
#define WRITE_A(BUF_)                                                                 \
  {                                                                                   \
    uint4 o;                                                                          \
    o.x = lerp_pair(g00.x, g01.x, g10.x, g11.x, w0, w1, w2, w3);                      \
    o.y = lerp_pair(g00.y, g01.y, g10.y, g11.y, w0, w1, w2, w3);                      \
    o.z = lerp_pair(g00.z, g01.z, g10.z, g11.z, w0, w1, w2, w3);                      \
    o.w = lerp_pair(g00.w, g01.w, g10.w, g11.w, w0, w1, w2, w3);                      \
    *(uint4*)&aLds[BUF_][gp * 40 + gq * 8] = o;                                       \
  }
  uint4 g00, g01, g10, g11;
  // prologue: phase 0 A into buf 0, prefetch phase 1 corners
  LOADP(0);
  g00 = *(const uint4*)(b00); g01 = *(const uint4*)(b01);
  g10 = *(const uint4*)(b10); g11 = *(const uint4*)(b11);
  WRITE_A(0);
  g00 = *(const uint4*)(b00 + 32); g01 = *(const uint4*)(b01 + 32);
  g10 = *(const uint4*)(b10 + 32); g11 = *(const uint4*)(b11 + 32);
  __syncthreads();

  for (int p = 0; p < 72; ++p) {
    int cur = p & 1;
    int tap = p >> 3, chunk = p & 7;
    const unsigned short* wp = wdb + (size_t)tap * 65536 + chunk * 8192;
    bf16x8 b[4], a[4];
#pragma unroll
    for (int j = 0; j < 4; ++j)
      b[j] = *(bf16x8*)&wp[(ns * 64 + 16 * j + l15) * 32 + l4 * 8];
#pragma unroll
    for (int i = 0; i < 4; ++i)
      a[i] = *(bf16x8*)&aLds[cur][(mh * 64 + 16 * i + l15) * 40 + l4 * 8];
#pragma unroll
    for (int i = 0; i < 4; ++i)
#pragma unroll
      for (int j = 0; j < 4; ++j)
        acc[i][j] = __builtin_amdgcn_mfma_f32_16x16x32_bf16(a[i], b[j], acc[i][j], 0, 0, 0);
    if (p < 71) {
      WRITE_A(cur ^ 1);
      int q = p + 2;
      if (q < 72) {
        int qt = q >> 3, qc = q & 7;
        if (qc == 0) LOADP(qt);
        int cio = qc * 32;
        g00 = *(const uint4*)(b00 + cio); g01 = *(const uint4*)(b01 + cio);
        g10 = *(const uint4*)(b10 + cio); g11 = *(const uint4*)(b11 + cio);
      }
    }
    __syncthreads(); // single barrier per phase
  }
#undef LOADP
#undef WRITE_A
  // epilogue: bias + raw bf16 store (NHWC) + fused BN1 partial stats
  sstat[t] = 0.f;
  __syncthreads();
  unsigned short* dst = y1r + ((size_t)(n * 4096 + ybase * 64) << 8);
#pragma unroll
  for (int j = 0; j < 4; ++j) {
    int co = ns * 64 + 16 * j + l15;
    float bias = b_dcn[co];
    float ss = 0.f, qq = 0.f;
#pragma unroll
    for (int i = 0; i < 4; ++i)
#pragma unroll
      for (int rr = 0; rr < 4; ++rr) {
        int pos = mh * 64 + 16 * i + l4 * 4 + rr;
        float v = acc[i][j][rr] + bias;
        dst[pos * 256 + co] = f2bf(v);
        ss += v; qq += v * v;
      }
    ss += __shfl_xor(ss, 16); ss += __shfl_xor(ss, 32);
    qq += __shfl_xor(qq, 16); qq += __shfl_xor(qq, 32);
    if (l4 == 0) { atomicAdd(&sstat[co], ss); atomicAdd(&sstat[256 + co], qq); }
  }
  __syncthreads();
  part1[(size_t)bid * 512 + t] = sstat[t];
}

// finalize from per-block partials (nblocks x [256 sum | 256 sumsq]).
__global__ __launch_bounds__(256) void k_finalize_p(const float* __restrict__ part,
                                                    const float* __restrict__ gamma,
                                                    const float* __restrict__ beta,
                                                    float* __restrict__ scsh,
                                                    float inv_cnt, int nblocks) {
  __shared__ float red[512];
  int c = blockIdx.x;
  int t = threadIdx.x;
  float s = 0.f, q = 0.f;
  for (int b = t; b < nblocks; b += 256) {
    s += part[(size_t)b * 512 + c];
    q += part[(size_t)b * 512 + 256 + c];
  }
  red[t] = s;
  red[256 + t] = q;
  __syncthreads();
  for (int w = 128; w > 0; w >>= 1) {
    if (t < w) { red[t] += red[t + w]; red[256 + t] += red[256 + t + w]; }
    __syncthreads();
  }
  if (t == 0) {
    float mu = red[0] * inv_cnt;
    float var = red[256] * inv_cnt - mu * mu;
    float r = rsqrtf(var + 1e-5f);
    float sc = gamma[c] * r;
    scsh[c] = sc;
    scsh[256 + c] = beta[c] - mu * sc;
  }
}

// ConvTranspose 4x4 s2 p1 via bf16 MFMA, u-block=2, DIRECT global W loads,
// BN1 norm+relu fused into A-stage, DOUBLE-BUFFERED aLds (1 barrier/chunk),
// fused BN2 partial stats. grid 512: bid&7=n, then py, ub(32).
__global__ __launch_bounds__(512) void k_convt2(const unsigned short* __restrict__ y1b,
                                               const unsigned short* __restrict__ wcb,
                                               const float* __restrict__ scsh1,
                                               float* __restrict__ out,
                                               float* __restrict__ part2) {
  __shared__ unsigned short sh[16896]; // 33792 B: 2x aLds (2*7920 ush) / epi (33792 B)
  __shared__ float sstat[512];

  int bid = blockIdx.x;
  int n = bid & 7;
  int r2 = bid >> 3;
  int py = r2 & 1;
  int ub = r2 >> 1;        // 0..31
  int u0 = ub * 2;
  int ry0 = u0 - 1 + py;   // rows ry0..ry0+2
  int t = threadIdx.x;
  int wave = t >> 6, lane = t & 63;
  int px_w = wave >> 2, ns = wave & 3;
  int co_base = ns * 64;
  int l15 = lane & 15, l4 = lane >> 4;

  // A-task decode (tasks t and t+512 when t<280), chunk-independent parts
  int as0 = t & 3, arc0 = t >> 2, ac0 = arc0 % 66, ar0 = arc0 / 66;
  int t2 = t + 512;
  int as1 = t2 & 3, arc1 = t2 >> 2, ac1 = arc1 % 66, ar1 = arc1 / 66;
  bool a1v = (t < 280);
  size_t nbase = (size_t)n * 4096;
  int ry_0 = ry0 + ar0, ry_1 = ry0 + ar1;
  bool av0 = (ry_0 >= 0) && (ry_0 < 64) && (ac0 - 1) >= 0 && (ac0 - 1) < 64;
  bool av1 = a1v && (ry_1 >= 0) && (ry_1 < 64) && (ac1 - 1) >= 0 && (ac1 - 1) < 64;
  const unsigned short* asrc0 = y1b + (nbase + (size_t)ry_0 * 64 + (ac0 - 1)) * 256 + as0 * 8;
  const unsigned short* asrc1 = y1b + (nbase + (size_t)ry_1 * 64 + (ac1 - 1)) * 256 + as1 * 8;
  int aoff0 = (ar0 * 66 + ac0) * 40 + as0 * 8;
  int aoff1 = (ar1 * 66 + ac1) * 40 + as1 * 8;

  f32x4 acc[2][4][4] = {}; // 128 VGPRs

  uint4 raw0, raw1;
#define NORMWRITE(BUF_, CHUNK_)                                                          \
  {                                                                                      \
    unsigned short* ab = sh + (BUF_)*7920;                                               \
    int cb0 = (CHUNK_)*32 + as0 * 8;                                                     \
    uint4 val = make_uint4(0u, 0u, 0u, 0u);                                              \
    if (av0) {                                                                           \
      float4 sc0 = *(const float4*)&scsh1[cb0];                                          \
      float4 sc1 = *(const float4*)&scsh1[cb0 + 4];                                      \
      float4 sh0 = *(const float4*)&scsh1[256 + cb0];                                    \
      float4 sh1 = *(const float4*)&scsh1[256 + cb0 + 4];                                \
      val.x = norm_pair(raw0.x, sc0.x, sh0.x, sc0.y, sh0.y);                             \
      val.y = norm_pair(raw0.y, sc0.z, sh0.z, sc0.w, sh0.w);                             \
      val.z = norm_pair(raw0.z, sc1.x, sh1.x, sc1.y, sh1.y);                             \
      val.w = norm_pair(raw0.w, sc1.z, sh1.z, sc1.w, sh1.w);                             \
    }                                                                                    \
    *(uint4*)&ab[aoff0] = val;                                                           \
    if (a1v) {                                                                           \
      int cb1 = (CHUNK_)*32 + as1 * 8;                                                   \
      uint4 v1 = make_uint4(0u, 0u, 0u, 0u);                                             \
      if (av1) {                                                                         \
        float4 sc0 = *(const float4*)&scsh1[cb1];                                        \
        float4 sc1 = *(const float4*)&scsh1[cb1 + 4];                                    \
        float4 sh0 = *(const float4*)&scsh1[256 + cb1];                                  \
        float4 sh1 = *(const float4*)&scsh1[256 + cb1 + 4];                              \
        v1.x = norm_pair(raw1.x, sc0.x, sh0.x, sc0.y, sh0.y);                            \
        v1.y = norm_pair(raw1.y, sc0.z, sh0.z, sc0.w, sh0.w);                            \
        v1.z = norm_pair(raw1.z, sc1.x, sh1.x, sc1.y, sh1.y);                            \
        v1.w = norm_pair(raw1.w, sc1.z, sh1.z, sc1.w, sh1.w);                            \
      }                                                                                  \
      *(uint4*)&ab[aoff1] = v1;                                                          \
    }                                                                                    \
  }

  // prologue: chunk0 raw -> norm+write buf0; prefetch chunk1 raw
  raw0 = av0 ? *(const uint4*)(asrc0) : make_uint4(0u, 0u, 0u, 0u);
  raw1 = av1 ? *(const uint4*)(asrc1) : make_uint4(0u, 0u, 0u, 0u);
  NORMWRITE(0, 0);
  raw0 = av0 ? *(const uint4*)(asrc0 + 32) : make_uint4(0u, 0u, 0u, 0u);
  raw1 = av1 ? *(const uint4*)(asrc1 + 32) : make_uint4(0u, 0u, 0u, 0u);
  __syncthreads();

  for (int chunk = 0; chunk < 8; ++chunk) {
    int cur = chunk & 1;
    const unsigned short* abuf = sh + cur * 7920;
    for (int tap = 0; tap < 4; ++tap) {
      int r_ofs = tap >> 1, s = tap & 1;
      const unsigned short* wsrc =
          wcb + ((size_t)((((py * 2 + px_w) * 4 + tap) * 8 + chunk) * 256 + co_base)) * 32;
      bf16x8 b[4];
#pragma unroll
      for (int j = 0; j < 4; ++j)
        b[j] = *(bf16x8*)&wsrc[(16 * j + l15) * 32 + l4 * 8];
#pragma unroll
      for (int k = 0; k < 2; ++k)
#pragma unroll
        for (int i = 0; i < 4; ++i) {
          int c = 16 * i + l15 + s + px_w;
          bf16x8 a = *(bf16x8*)&abuf[((k + r_ofs) * 66 + c) * 40 + l4 * 8];
#pragma unroll
          for (int j = 0; j < 4; ++j)
            acc[k][i][j] = __builtin_amdgcn_mfma_f32_16x16x32_bf16(a, b[j], acc[k][i][j], 0, 0, 0);
        }
    }
    if (chunk < 7) {
      NORMWRITE(cur ^ 1, chunk + 1);
      if (chunk < 6) {
        int nc = (chunk + 2) * 32;
        raw0 = av0 ? *(const uint4*)(asrc0 + nc) : make_uint4(0u, 0u, 0u, 0u);
        raw1 = av1 ? *(const uint4*)(asrc1 + nc) : make_uint4(0u, 0u, 0u, 0u);
      }
    }
    __syncthreads(); // single barrier per chunk
  }
#undef NORMWRITE

  // epilogue: px interleave via LDS, contiguous stores, fused BN2 partials.
  sstat[t] = 0.f;
  float* epi = (float*)sh;
#pragma unroll
  for (int k = 0; k < 2; ++k) {
    int oy = 2 * (u0 + k) + py;
    for (int qt = 0; qt < 4; ++qt) {
      __syncthreads();
      if (ns == qt) {
#pragma unroll
        for (int i = 0; i < 4; ++i)
#pragma unroll
          for (int j = 0; j < 4; ++j) {
            int co_l = 16 * j + l15;
            int vbase = 16 * i + l4 * 4;
            *(f32x4*)&epi[co_l * 132 + px_w * 64 + vbase] = acc[k][i][j];
          }
      }
      __syncthreads();
#pragma unroll
      for (int it = 0; it < 4; ++it) {
        int task = it * 512 + t;
        int q = task & 31;
        int co_l = task >> 5;
        int co = qt * 64 + co_l;
        float e00 = epi[co_l * 132 + 2 * q];
        float e01 = epi[co_l * 132 + 2 * q + 1];
        float e10 = epi[co_l * 132 + 64 + 2 * q];
        float e11 = epi[co_l * 132 + 64 + 2 * q + 1];
        float4 vv = make_float4(e00, e10, e01, e11);
        *(float4*)&out[((size_t)(n * 256 + co) * 128 + oy) * 128 + 4 * q] = vv;
        float ss = e00 + e01 + e10 + e11;
        float qq = e00 * e00 + e01 * e01 + e10 * e10 + e11 * e11;
        ss += __shfl_xor(ss, 1);  qq += __shfl_xor(qq, 1);
        ss += __shfl_xor(ss, 2);  qq += __shfl_xor(qq, 2);
        ss += __shfl_xor(ss, 4);  qq += __shfl_xor(qq, 4);
        ss += __shfl_xor(ss, 8);  qq += __shfl_xor(qq, 8);
        ss += __shfl_xor(ss, 16); qq += __shfl_xor(qq, 16);
        if ((lane & 31) == 0) {
          atomicAdd(&sstat[co], ss);
          atomicAdd(&sstat[256 + co], qq);
        }
      }
    }
  }
  __syncthreads();
  part2[(size_t)bid * 512 + t] = sstat[t];
}

__global__ void k_norm_nchw(float* __restrict__ buf, const float* __restrict__ scsh) {
  int idx = blockIdx.x * 256 + threadIdx.x;
  int c = (idx >> 12) & 255;
  float sc = scsh[c], sh = scsh[256 + c];
  float4 v = *(float4*)&buf[(size_t)idx * 4];
  v.x = fmaxf(fmaf(v.x, sc, sh), 0.f);
  v.y = fmaxf(fmaf(v.y, sc, sh), 0.f);
  v.z = fmaxf(fmaf(v.z, sc, sh), 0.f);
  v.w = fmaxf(fmaf(v.w, sc, sh), 0.f);
  *(float4*)&buf[(size_t)idx * 4] = v;
}

extern "C" void kernel_launch(void* const* d_in, const int* in_sizes, int n_in,
                              void* d_out, int out_size, void* d_ws, size_t ws_size,
                              hipStream_t stream) {
  (void)in_sizes; (void)n_in; (void)out_size; (void)ws_size;
  const float* x      = (const float*)d_in[0];
  const float* w_off  = (const float*)d_in[1];
  const float* b_off  = (const float*)d_in[2];
  const float* w_dcn  = (const float*)d_in[3];
  const float* b_dcn  = (const float*)d_in[4];
  const float* gamma1 = (const float*)d_in[5];
  const float* beta1  = (const float*)d_in[6];
  const float* w_ct   = (const float*)d_in[7];
  const float* gamma2 = (const float*)d_in[8];
  const float* beta2  = (const float*)d_in[9];
  float* ws  = (float*)d_ws;
  unsigned short* xtb = (unsigned short*)(ws + OFF_XT);
  unsigned short* y1r = (unsigned short*)(ws + OFF_Y1);
  float* om  = ws + OFF_OM;           // reused as part2 after dcn2
  unsigned short* wdb = (unsigned short*)(ws + OFF_WD);
  unsigned short* wcb = (unsigned short*)(ws + OFF_WC);
  unsigned short* wob = (unsigned short*)(ws + OFF_WO);
  float* st  = ws + OFF_ST;
  float* p1  = ws + OFF_P1;
  float* out = (float*)d_out;

  k_transpose_x<<<dim3(512, 8, 2), 256, 0, stream>>>(x, xtb);
  k_prep_wdcn<<<2304, 256, 0, stream>>>(w_dcn, wdb);
  k_prep_wct<<<4096, 256, 0, stream>>>(w_ct, wcb);
  k_prep_woff<<<288, 256, 0, stream>>>(w_off, wob);
  k_offset_mfma<<<128, 512, 0, stream>>>(xtb, wob, b_off, om);
  k_dcn2<<<256, 512, 0, stream>>>(xtb, om, wdb, b_dcn, y1r, p1);
  k_finalize_p<<<256, 256, 0, stream>>>(p1, gamma1, beta1, st + 512, 1.f / 32768.f, 256);
  k_convt2<<<512, 512, 0, stream>>>(y1r, wcb, st + 512, out, om); // om reused as part2
  k_finalize_p<<<256, 256, 0, stream>>>(om, gamma2, beta2, st + 1536, 1.f / 131072.f, 512);
  k_norm_nchw<<<32768, 256, 0, stream>>>(out, st + 1536);
}